// Round 9
// baseline (220.646 us; speedup 1.0000x reference)
//
#include <hip/hip_runtime.h>
#include <hip/hip_bf16.h>

// FactoredHmmLm forward on MI355X.
//  1. prep_k: weight-cvt + embeddings + CSR + esum-zero (one launch)
//  2. residual MLPs: batched mlp_k<1>/<2> (blockIdx.z = chain)
//  3. rlse_k: 256x256-tile GEMM, counted-vmcnt, 2D-XCD-region swizzle
//  4. emis_k: MFMA 64-word blocks (gl2lds gathered staging) + atomic exp-sum
//  5. leaf_k: M_t = exp(tr - rlse + emit - m), emit computed inline
//  6. comb4 x2 levels + tail_k (last 2 levels + hlse + final, 16 blocks)

using u16 = unsigned short;
typedef __attribute__((ext_vector_type(8))) short bh8;     // 8 bf16 (4 VGPRs)
typedef __attribute__((ext_vector_type(4))) float f32x4;
typedef __attribute__((ext_vector_type(8))) unsigned short u16x8;

#define HD 256
#define TT 256
#define NB 16
#define KCL 128
#define CS 8192
#define VV 10000
#define MAXB 320
#define LOG2E 1.44269504f
#define WTOT (6 * 65536)
#define WT2  (WTOT + VV * HD)                 // 2,953,216 (mult of 2048)
#define NCVT (WT2 / 2048)                     // 1442 blocks (8 elem/thread)
#define NEMB (4 * CS * HD / 2048)             // 4096 blocks

__device__ __forceinline__ u16 f2bf(float v) {
  union { float f; unsigned int i; } u; u.f = v;
  unsigned int r = u.i + 0x7fffu + ((u.i >> 16) & 1u);   // RNE
  return (u16)(r >> 16);
}
__device__ __forceinline__ float bf2f(u16 u) {
  union { unsigned int i; float f; } x; x.i = ((unsigned int)u) << 16; return x.f;
}
__device__ __forceinline__ void gl2lds16(const u16* g, u16* l) {
  __builtin_amdgcn_global_load_lds(
      (const __attribute__((address_space(1))) unsigned int*)g,
      (__attribute__((address_space(3))) unsigned int*)l, 16, 0, 0);
}
__device__ __forceinline__ u16x8 cvt8(const float* __restrict__ s) {
  const float4 a = *reinterpret_cast<const float4*>(s);
  const float4 b = *reinterpret_cast<const float4*>(s + 4);
  u16x8 o;
  o[0] = f2bf(a.x); o[1] = f2bf(a.y); o[2] = f2bf(a.z); o[3] = f2bf(a.w);
  o[4] = f2bf(b.x); o[5] = f2bf(b.y); o[6] = f2bf(b.z); o[7] = f2bf(b.w);
  return o;
}
__device__ __forceinline__ u16x8 add_cvt8(const float* __restrict__ s0,
                                          const float* __restrict__ s1) {
  const float4 a0 = *reinterpret_cast<const float4*>(s0);
  const float4 b0 = *reinterpret_cast<const float4*>(s0 + 4);
  const float4 a1 = *reinterpret_cast<const float4*>(s1);
  const float4 b1 = *reinterpret_cast<const float4*>(s1 + 4);
  u16x8 o;
  o[0] = f2bf(a0.x + a1.x); o[1] = f2bf(a0.y + a1.y);
  o[2] = f2bf(a0.z + a1.z); o[3] = f2bf(a0.w + a1.w);
  o[4] = f2bf(b0.x + b1.x); o[5] = f2bf(b0.y + b1.y);
  o[6] = f2bf(b0.z + b1.z); o[7] = f2bf(b0.w + b1.w);
  return o;
}

// ---------------- prep: weights->bf16, embeddings, CSR, esum zero ----------------

__global__ __launch_bounds__(256) void prep_k(
    const float* __restrict__ w0, const float* __restrict__ w1,
    const float* __restrict__ w2, const float* __restrict__ w3,
    const float* __restrict__ w4, const float* __restrict__ w5,
    const float* __restrict__ tpw, u16* __restrict__ dstW,
    const float* __restrict__ ec0, const float* __restrict__ es0, u16* __restrict__ d0,
    const float* __restrict__ ec1, const float* __restrict__ es1, u16* __restrict__ d1,
    const float* __restrict__ ec2, const float* __restrict__ es2, u16* __restrict__ d2,
    const float* __restrict__ ec3, const float* __restrict__ es3, u16* __restrict__ d3,
    const int* __restrict__ w2c, int* __restrict__ offs,
    int* __restrict__ wlist, int* __restrict__ bmap, float* __restrict__ esum) {
  const int b = blockIdx.x, tid = threadIdx.x;
  if (b < NCVT) {
    const int idx = (b * 256 + tid) * 8;
    const float* src;
    if (idx < WTOT) {
      const int i = idx >> 16;
      const float* s = i == 0 ? w0 : i == 1 ? w1 : i == 2 ? w2 : i == 3 ? w3 : i == 4 ? w4 : w5;
      src = s + (idx & 65535);
    } else {
      src = tpw + (idx - WTOT);
    }
    *reinterpret_cast<u16x8*>(dstW + idx) = cvt8(src);
  } else if (b < NCVT + NEMB) {
    const int idx = ((b - NCVT) * 256 + tid) * 8;
    const int seg = idx >> 21;
    const int off = idx & ((CS * HD) - 1);
    const int h = off & 255, row = off >> 8;
    const int k = row >> 6, s = row & 63;
    const float* ec = seg == 0 ? ec0 : seg == 1 ? ec1 : seg == 2 ? ec2 : ec3;
    const float* es = seg == 0 ? es0 : seg == 1 ? es1 : seg == 2 ? es2 : es3;
    u16* d = seg == 0 ? d0 : seg == 1 ? d1 : seg == 2 ? d2 : d3;
    *reinterpret_cast<u16x8*>(d + off) = add_cvt8(ec + k * HD + h, es + s * HD + h);
  } else if (b == NCVT + NEMB) {
    __shared__ int cnt[KCL], cur[KCL], off_s[KCL + 1];
    if (tid < KCL) cnt[tid] = 0;
    __syncthreads();
    for (int w = tid; w < VV; w += 256) atomicAdd(&cnt[w2c[w]], 1);
    __syncthreads();
    if (tid == 0) {
      int acc = 0;
      for (int c = 0; c < KCL; ++c) { off_s[c] = acc; acc += cnt[c]; }
      off_s[KCL] = acc;
      int idx = 0;
      for (int c = 0; c < KCL; ++c) {
        const int nb = (cnt[c] + 63) >> 6;
        for (int bb = 0; bb < nb; ++bb) bmap[idx++] = (c << 8) | bb;
      }
      for (; idx < MAXB; ++idx) bmap[idx] = -1;
    }
    __syncthreads();
    if (tid < KCL) cur[tid] = off_s[tid];
    if (tid <= KCL) offs[tid] = off_s[tid];
    __syncthreads();
    for (int w = tid; w < VV; w += 256) {
      const int p = atomicAdd(&cur[w2c[w]], 1);
      wlist[p] = w;
    }
  } else {
    for (int i = tid; i < CS; i += 256) esum[i] = 0.f;
  }
}

// ---------------- batched residual-MLP GEMMs: z = chain (start/trans/term) ----------

template<int LAYER>
__global__ __launch_bounds__(256) void mlp_k(
    const u16* __restrict__ E0, const u16* __restrict__ E1, const u16* __restrict__ E2,
    u16* __restrict__ H0, u16* __restrict__ H1, u16* __restrict__ H2,
    const u16* __restrict__ Wall,
    const float* __restrict__ bb0, const float* __restrict__ bb1, const float* __restrict__ bb2,
    float* __restrict__ SHf, u16* __restrict__ Xbf, u16* __restrict__ PHb) {
  __shared__ char lds[16384];
  const int tid = threadIdx.x, lane = tid & 63, wid = tid >> 6;
  const int z = blockIdx.z;
  const u16* Eb = z == 0 ? E0 : z == 1 ? E1 : E2;
  u16* Hb = z == 0 ? H0 : z == 1 ? H1 : H2;
  const u16* A = (LAYER == 1) ? Eb : (const u16*)Hb;
  const u16* B = Wall + (size_t)(2 * z + (LAYER - 1)) * 65536;
  const float* bias = z == 0 ? bb0 : z == 1 ? bb1 : bb2;

  const int rm = blockIdx.y * 64, cn = blockIdx.x * 64;
  const u16* Ag = A + (size_t)rm * HD;
  const u16* Bg = B + (size_t)cn * HD;

  f32x4 acc[4];
#pragma unroll
  for (int i = 0; i < 4; ++i) acc[i] = (f32x4){0.f, 0.f, 0.f, 0.f};
  const int ra = wid * 16 + (lane & 15);
  const int rb0 = lane & 15;
  const int ko = (lane >> 4) * 8;

  for (int kc = 0; kc < HD; kc += 64) {
    if (kc) __syncthreads();
#pragma unroll
    for (int i = 0; i < 2; ++i) {
      const int c = i * 256 + tid;
      const int r = c >> 3, cb = c & 7;
      const int gq = cb ^ (r & 7);
      gl2lds16(Ag + (size_t)r * HD + kc + gq * 8, (u16*)&lds[c * 16]);
      gl2lds16(Bg + (size_t)r * HD + kc + gq * 8, (u16*)&lds[8192 + c * 16]);
    }
    __syncthreads();
#pragma unroll
    for (int kk = 0; kk < 64; kk += 32) {
      const int kb = (kk + ko) * 2;
      const bh8 af = *reinterpret_cast<const bh8*>(&lds[ra * 128 + (kb ^ ((ra & 7) << 4))]);
#pragma unroll
      for (int nj = 0; nj < 4; ++nj) {
        const int rb = nj * 16 + rb0;
        const bh8 bf = *reinterpret_cast<const bh8*>(&lds[8192 + rb * 128 + (kb ^ ((rb & 7) << 4))]);
        acc[nj] = __builtin_amdgcn_mfma_f32_16x16x32_bf16(af, bf, acc[nj], 0, 0, 0);
      }
    }
  }

  const int g = lane >> 4, c0 = lane & 15;
#pragma unroll
  for (int nj = 0; nj < 4; ++nj) {
    const int nidx = cn + nj * 16 + c0;
    const float bv = bias[nidx];
#pragma unroll
    for (int reg = 0; reg < 4; ++reg) {
      const int midx = rm + wid * 16 + g * 4 + reg;
      float v = acc[nj][reg] + bv;
      if (LAYER == 2) v += bf2f(Eb[(size_t)midx * 256 + nidx]);
      v = fmaxf(v, 0.f);
      if (LAYER == 1) {
        Hb[(size_t)midx * 256 + nidx] = f2bf(v);
      } else {
        if (z == 0) SHf[(size_t)midx * 256 + nidx] = v;
        else if (z == 1) Xbf[(size_t)midx * 256 + nidx] = f2bf(v);
        else PHb[(size_t)midx * 256 + nidx] = f2bf(v);
      }
    }
  }
}

// ---------------- transition row-lse: 256x256-tile, 2D-XCD regions, counted vmcnt -------

__global__ __launch_bounds__(512) void rlse_k(const u16* __restrict__ A,
                                              const u16* __restrict__ B,
                                              float* __restrict__ part) {
  __shared__ char lds[131072];   // [2 bufs][ A 32KB | B 32KB ]
  const int tid = threadIdx.x;
  const int lane = tid & 63, w = tid >> 6;   // 8 waves
  const int wr = w >> 2, wc = w & 3;          // 2M x 4N
  const int c0 = lane & 15, g = lane >> 4;

  // 2D XCD regions: XCD (bid&7) owns a 16(by) x 8(bx) tile rectangle.
  // Working set per XCD: 16*128KB A + 8*128KB B = 3 MB < 4 MB L2.
  const int bid = blockIdx.x;                  // 1024 = 32x32 tiles
  const int xcd = bid & 7, idx = bid >> 3;     // idx 0..127
  const int by = (xcd >> 2) * 16 + (idx >> 3);
  const int bx = (xcd & 3) * 8 + (idx & 7);
  const int rm = by * 256, cn = bx * 256;

  f32x4 acc[8][4];
#pragma unroll
  for (int i = 0; i < 8; ++i)
#pragma unroll
    for (int j = 0; j < 4; ++j) acc[i][j] = (f32x4){0.f, 0.f, 0.f, 0.f};

  auto STAGE = [&](int kt, int hb) {
    const int kc = kt * 64;
    const int bo = hb * 65536;
#pragma unroll
    for (int q = 0; q < 4; ++q) {
      const int c = q * 512 + tid;
      const int r = c >> 3, cb = c & 7;
      const int gq = cb ^ (r & 7);
      gl2lds16(A + (size_t)(rm + r) * HD + kc + gq * 8, (u16*)&lds[bo + c * 16]);
    }
#pragma unroll
    for (int q = 0; q < 4; ++q) {
      const int c = q * 512 + tid;
      const int r = c >> 3, cb = c & 7;
      const int gq = cb ^ (r & 7);
      gl2lds16(B + (size_t)(cn + r) * HD + kc + gq * 8, (u16*)&lds[bo + 32768 + c * 16]);
    }
  };

  STAGE(0, 0);
  STAGE(1, 1);

  int cur = 0;
  for (int kt = 0; kt < 4; ++kt) {
    if (kt < 3) asm volatile("s_waitcnt vmcnt(8)" ::: "memory");
    else        asm volatile("s_waitcnt vmcnt(0)" ::: "memory");
    __builtin_amdgcn_sched_barrier(0);
    __builtin_amdgcn_s_barrier();
    const int bo = cur * 65536;
    __builtin_amdgcn_s_setprio(1);
#pragma unroll
    for (int kk = 0; kk < 64; kk += 32) {
      const int kb = (kk + g * 8) * 2;
      bh8 af[8], bf[4];
#pragma unroll
      for (int mi = 0; mi < 8; ++mi) {
        const int ar = wr * 128 + mi * 16 + c0;
        af[mi] = *reinterpret_cast<const bh8*>(&lds[bo + ar * 128 + (kb ^ ((ar & 7) << 4))]);
      }
#pragma unroll
      for (int nj = 0; nj < 4; ++nj) {
        const int br = wc * 64 + nj * 16 + c0;
        bf[nj] = *reinterpret_cast<const bh8*>(&lds[bo + 32768 + br * 128 + (kb ^ ((br & 7) << 4))]);
      }
#pragma unroll
      for (int mi = 0; mi < 8; ++mi)
#pragma unroll
        for (int nj = 0; nj < 4; ++nj)
          acc[mi][nj] = __builtin_amdgcn_mfma_f32_16x16x32_bf16(af[mi], bf[nj], acc[mi][nj], 0, 0, 0);
    }
    __builtin_amdgcn_s_setprio(0);
    __builtin_amdgcn_s_barrier();
    __builtin_amdgcn_sched_barrier(0);
    if (kt < 2) STAGE(kt + 2, cur);
    cur ^= 1;
  }

  float rs[8][4];
#pragma unroll
  for (int mi = 0; mi < 8; ++mi)
#pragma unroll
    for (int reg = 0; reg < 4; ++reg) {
      float s = 0.f;
#pragma unroll
      for (int nj = 0; nj < 4; ++nj) s += exp2f(acc[mi][nj][reg] * LOG2E);
      rs[mi][reg] = s;
    }
#pragma unroll
  for (int off = 1; off < 16; off <<= 1)
#pragma unroll
    for (int mi = 0; mi < 8; ++mi)
#pragma unroll
      for (int reg = 0; reg < 4; ++reg)
        rs[mi][reg] += __shfl_xor(rs[mi][reg], off, 64);

  float* Lf = reinterpret_cast<float*>(lds);   // [256][4]
  if (c0 == 0) {
#pragma unroll
    for (int mi = 0; mi < 8; ++mi)
#pragma unroll
      for (int reg = 0; reg < 4; ++reg)
        Lf[(wr * 128 + mi * 16 + g * 4 + reg) * 4 + wc] = rs[mi][reg];
  }
  __syncthreads();
  if (tid < 256)
    part[(size_t)bx * CS + rm + tid] = Lf[tid * 4] + Lf[tid * 4 + 1] + Lf[tid * 4 + 2] + Lf[tid * 4 + 3];
}

__global__ void rred_k(const float* __restrict__ part, float* __restrict__ rlse) {
  const int i = blockIdx.x * 256 + threadIdx.x;
  float s = 0.f;
#pragma unroll 8
  for (int b = 0; b < 32; ++b) s += part[(size_t)b * CS + i];
  rlse[i] = logf(s);
}

// ---------------- leaf-gen GEMM 64x64 tile (emit inline) ----------------

__global__ __launch_bounds__(256) void leaf_k(
    const u16* __restrict__ A, const u16* __restrict__ B,
    const float* __restrict__ row_lse,
    const float* __restrict__ lall, const float* __restrict__ esum,
    const int* __restrict__ text, const int* __restrict__ w2c,
    u16* __restrict__ leafb, float* __restrict__ leafsc) {
  __shared__ char lds[16384];
  __shared__ float wmax[4];
  const int tid = threadIdx.x;
  const int lane = tid & 63;
  const int wid = tid >> 6;

  const int bi = blockIdx.x;
  if (bi >= NB * (TT - 1)) {               // identity leaf
    const int n = bi - NB * (TT - 1);
    if (n < NB) {
      u16* node = leafb + ((size_t)n * 256 + 255) * 4096;
      for (int c = tid; c < 4096; c += 256) node[c] = ((c >> 6) == (c & 63)) ? (u16)0x3F80 : (u16)0;
      if (tid == 0) leafsc[n * 256 + 255] = 0.f;
    }
    return;
  }
  const int nn = bi / (TT - 1);
  const int ttv = bi % (TT - 1) + 1;
  const int wcur = text[nn * TT + ttv];
  const int rm = w2c[text[nn * TT + ttv - 1]] * 64;
  const int cn = w2c[wcur] * 64;
  const u16* Ag = A + (size_t)rm * HD;
  const u16* Bg = B + (size_t)cn * HD;

  f32x4 acc[4];
#pragma unroll
  for (int i = 0; i < 4; ++i) acc[i] = (f32x4){0.f, 0.f, 0.f, 0.f};
  const int ra = wid * 16 + (lane & 15);
  const int rb0 = lane & 15;
  const int ko = (lane >> 4) * 8;

  for (int kc = 0; kc < HD; kc += 64) {
    if (kc) __syncthreads();
#pragma unroll
    for (int i = 0; i < 2; ++i) {
      const int c = i * 256 + tid;
      const int r = c >> 3, cb = c & 7;
      const int gq = cb ^ (r & 7);
      gl2lds16(Ag + (size_t)r * HD + kc + gq * 8, (u16*)&lds[c * 16]);
      gl2lds16(Bg + (size_t)r * HD + kc + gq * 8, (u16*)&lds[8192 + c * 16]);
    }
    __syncthreads();
#pragma unroll
    for (int kk = 0; kk < 64; kk += 32) {
      const int kb = (kk + ko) * 2;
      const bh8 af = *reinterpret_cast<const bh8*>(&lds[ra * 128 + (kb ^ ((ra & 7) << 4))]);
#pragma unroll
      for (int nj = 0; nj < 4; ++nj) {
        const int rb = nj * 16 + rb0;
        const bh8 bf = *reinterpret_cast<const bh8*>(&lds[8192 + rb * 128 + (kb ^ ((rb & 7) << 4))]);
        acc[nj] = __builtin_amdgcn_mfma_f32_16x16x32_bf16(af, bf, acc[nj], 0, 0, 0);
      }
    }
  }

  const int g = lane >> 4, c0 = lane & 15;
  float L[4][4];
  float mx = -1e30f;
#pragma unroll
  for (int nj = 0; nj < 4; ++nj) {
    const int col = nj * 16 + c0;
    const float ev = lall[(size_t)wcur * 64 + col] - logf(esum[cn + col]);
#pragma unroll
    for (int reg = 0; reg < 4; ++reg) {
      const float l = acc[nj][reg] - row_lse[rm + wid * 16 + g * 4 + reg] + ev;
      L[nj][reg] = l;
      mx = fmaxf(mx, l);
    }
  }
#pragma unroll
  for (int off = 1; off < 64; off <<= 1) mx = fmaxf(mx, __shfl_xor(mx, off, 64));
  if (lane == 0) wmax[wid] = mx;
  __syncthreads();
  const float m = fmaxf(fmaxf(wmax[0], wmax[1]), fmaxf(wmax[2], wmax[3]));
  float* ftile = reinterpret_cast<float*>(lds);
#pragma unroll
  for (int nj = 0; nj < 4; ++nj)
#pragma unroll
    for (int reg = 0; reg < 4; ++reg)
      ftile[(wid * 16 + g * 4 + reg) * 64 + nj * 16 + c0] = exp2f((L[nj][reg] - m) * LOG2E);
  __syncthreads();
  const int leaf = ttv - 1;
  u16* node = leafb + ((size_t)nn * 256 + leaf) * 4096;
  const int rr = tid >> 2, cb = (tid & 3) * 16;
  u16x8 o0, o1;
  if ((leaf & 1) == 0) {
#pragma unroll
    for (int e = 0; e < 8; ++e) o0[e] = f2bf(ftile[rr * 64 + cb + e]);
#pragma unroll
    for (int e = 0; e < 8; ++e) o1[e] = f2bf(ftile[rr * 64 + cb + 8 + e]);
  } else {
#pragma unroll
    for (int e = 0; e < 8; ++e) o0[e] = f2bf(ftile[(cb + e) * 64 + rr]);
#pragma unroll
    for (int e = 0; e < 8; ++e) o1[e] = f2bf(ftile[(cb + 8 + e) * 64 + rr]);
  }
  *reinterpret_cast<u16x8*>(node + rr * 64 + cb) = o0;
  *reinterpret_cast<u16x8*>(node + rr * 64 + cb + 8) = o1;
  if (tid == 0) leafsc[nn * 256 + leaf] = m;
}

// ---------------- quad combine body: out = (M0*M1)*(M2*M3) ----------------

__device__ __forceinline__ void comb4_body(
    char* lds, float* wpm,
    const u16* s0, const u16* s1, const u16* s2, const u16* s3,
    float sc0, float sc1, float sc2, float sc3,
    u16* node, float* dsc, int parity, int tid) {
  const int lane = tid & 63, w = tid >> 6;
  const u16* srcs[4] = {s0, s1, s2, s3};
  const int sr = tid >> 3, scb = (tid & 7) * 16;
#pragma unroll
  for (int nd = 0; nd < 4; ++nd)
#pragma unroll
    for (int rep = 0; rep < 2; ++rep) {
      const int r = rep * 32 + sr;
      const bh8 v = *reinterpret_cast<const bh8*>(srcs[nd] + r * 64 + (scb >> 1));
      *reinterpret_cast<bh8*>(&lds[nd * 8192 + r * 128 + (scb ^ ((r & 7) << 4))]) = v;
    }
  __syncthreads();

  const int p = w >> 1, h = w & 1;
  const int abase = p * 16384, bbase = abase + 8192;
  const int c0 = lane & 15, g = lane >> 4;
  f32x4 a2[2][4];
#pragma unroll
  for (int mi = 0; mi < 2; ++mi)
#pragma unroll
    for (int nj = 0; nj < 4; ++nj) a2[mi][nj] = (f32x4){0.f, 0.f, 0.f, 0.f};
#pragma unroll
  for (int kk = 0; kk < 64; kk += 32) {
    const int kb = (kk + g * 8) * 2;
    bh8 af[2], bf[4];
#pragma unroll
    for (int mi = 0; mi < 2; ++mi) {
      const int ar = h * 32 + mi * 16 + c0;
      af[mi] = *reinterpret_cast<const bh8*>(&lds[abase + ar * 128 + (kb ^ ((ar & 7) << 4))]);
    }
#pragma unroll
    for (int nj = 0; nj < 4; ++nj) {
      const int br = nj * 16 + c0;
      bf[nj] = *reinterpret_cast<const bh8*>(&lds[bbase + br * 128 + (kb ^ ((br & 7) << 4))]);
    }
#pragma unroll
    for (int mi = 0; mi < 2; ++mi)
#pragma unroll
      for (int nj = 0; nj < 4; ++nj)
        a2[mi][nj] = __builtin_amdgcn_mfma_f32_16x16x32_bf16(af[mi], bf[nj], a2[mi][nj], 0, 0, 0);
  }
  float mx = 0.f;
#pragma unroll
  for (int mi = 0; mi < 2; ++mi)
#pragma unroll
    for (int nj = 0; nj < 4; ++nj)
#pragma unroll
      for (int reg = 0; reg < 4; ++reg) mx = fmaxf(mx, a2[mi][nj][reg]);
#pragma unroll
  for (int off = 1; off < 64; off <<= 1) mx = fmaxf(mx, __shfl_xor(mx, off, 64));
  if (lane == 0) wpm[w] = mx;
  __syncthreads();
  const float mp = fmaxf(wpm[p * 2], wpm[p * 2 + 1]);
  const float invp = 1.0f / mp;
#pragma unroll
  for (int mi = 0; mi < 2; ++mi)
#pragma unroll
    for (int nj = 0; nj < 4; ++nj)
#pragma unroll
      for (int reg = 0; reg < 4; ++reg) {
        const int row = h * 32 + mi * 16 + g * 4 + reg;
        const int col = nj * 16 + c0;
        const u16 val = f2bf(a2[mi][nj][reg] * invp);
        if (p == 0)
          *reinterpret_cast<u16*>(&lds[32768 + row * 128 + ((col * 2) ^ ((row & 7) << 4))]) = val;
        else
          *reinterpret_cast<u16*>(&lds[40960 + col * 128 + ((row * 2) ^ ((col & 7) << 4))]) = val;
      }
  __syncthreads();

  f32x4 acc[4];
#pragma unroll
  for (int i = 0; i < 4; ++i) acc[i] = (f32x4){0.f, 0.f, 0.f, 0.f};
  const int ra = w * 16 + c0;
#pragma unroll
  for (int kk = 0; kk < 64; kk += 32) {
    const int kb = (kk + g * 8) * 2;
    const bh8 af = *reinterpret_cast<const bh8*>(&lds[32768 + ra * 128 + (kb ^ ((ra & 7) << 4))]);
#pragma unroll
    for (int nj = 0; nj < 4; ++nj) {
      const int rb = nj * 16 + c0;
      const bh8 bf = *reinterpret_cast<const bh8*>(&lds[40960 + rb * 128 + (kb ^ ((rb & 7) << 4))]);
      acc[nj] = __builtin_amdgcn_mfma_f32_16x16x32_bf16(af, bf, acc[nj], 0, 0, 0);
    }
  }
  float mx2 = 0.f;
#pragma unroll
  for (int nj = 0; nj < 4; ++nj)
#pragma unroll
    for (int reg = 0; reg < 4; ++reg) mx2 = fmaxf(mx2, acc[nj][reg]);
#pragma unroll
  for (int off = 1; off < 64; off <<= 1) mx2 = fmaxf(mx2, __shfl_xor(mx2, off, 64));
  if (lane == 0) wpm[4 + w] = mx2;
  __syncthreads();
  const float m = fmaxf(fmaxf(wpm[4], wpm[5]), fmaxf(wpm[6], wpm[7]));
  const float inv = 1.0f / m;
  float* ftile = reinterpret_cast<float*>(lds);
#pragma unroll
  for (int nj = 0; nj < 4; ++nj)
#pragma unroll
    for (int reg = 0; reg < 4; ++reg)
      ftile[(w * 16 + g * 4 + reg) * 64 + nj * 16 + c0] = acc[nj][reg] * inv;
  __syncthreads();
  const int rr = tid >> 2, cb = (tid & 3) * 16;
  u16x8 o0, o1;
  if (parity == 0) {
#pragma unroll
    for (int e = 0; e < 8; ++e) o0[e] = f2bf(ftile[rr * 64 + cb + e]);
#pragma unroll
    for (int e = 0; e < 8; ++e) o1[e] = f2bf(ftile[rr * 64 + cb + 8 + e]);
  } else {
#pragma unroll
    for (int e = 0; e < 8; ++e) o0[e] = f2bf(ftile[(cb + e) * 64 + rr]);
#pragma unroll
    for (int e = 0; e < 8; ++e) o1[e] = f2bf(ftile[(cb + 8 + e) * 64 + rr]);
  }
  *reinterpret_cast<u16x8*>(node + rr * 64 + cb) = o0;
  *reinterpret_cast<u16x8*>(node + rr * 64 + cb + 8) = o1;
  if (tid == 0)
    *dsc = sc0 + sc1 + sc2 + sc3
         + logf(fmaxf(wpm[0], wpm[1])) + logf(fmaxf(wpm[2], wpm[3])) + logf(m);
}

__global__ __launch_bounds__(256) void comb4_k(const u16* __restrict__ src,
                                               const float* __restrict__ scs,
                                               u16* __restrict__ dst,
                                               float* __restrict__ scd, int U) {
  const int n = blockIdx.x / U, u = blockIdx.x % U;
  __shared__ char lds[49152];
  __shared__ float wpm[8];
  const u16* base = src + ((size_t)(n * 4 * U + 4 * u)) * 4096;
  const float* sb = scs + n * 4 * U + 4 * u;
  comb4_body(lds, wpm, base, base + 4096, base + 2 * 4096, base + 3 * 4096,
             sb[0], sb[1], sb[2], sb[3],
             dst + ((size_t)(n * U + u)) * 4096, &scd[n * U + u], u & 1, threadIdx.x);
}

// ---------------- tail: last 2 levels + hlse + final (16 blocks) ----------------

__global__ __launch_bounds__(256) void tail_k(
    const u16* __restrict__ nodes, const float* __restrict__ nsc,
    u16* __restrict__ scratch, float* __restrict__ ssc,
    const float* __restrict__ hlog, const float* __restrict__ lall,
    const float* __restrict__ esum, const int* __restrict__ text,
    const int* __restrict__ w2c, float* __restrict__ out) {
  __shared__ char lds[49152];
  __shared__ float wpm[8];
  __shared__ float redm[4];
  __shared__ float hl_s;
  const int n = blockIdx.x, tid = threadIdx.x;
  const int lane = tid & 63, w = tid >> 6;

  // hlse over hlog[8192]
  float mm = -1e30f;
  for (int i = tid; i < CS; i += 256) mm = fmaxf(mm, hlog[i]);
  for (int off = 32; off; off >>= 1) mm = fmaxf(mm, __shfl_xor(mm, off, 64));
  if (lane == 0) redm[w] = mm;
  __syncthreads();
  const float M = fmaxf(fmaxf(redm[0], redm[1]), fmaxf(redm[2], redm[3]));
  float sx = 0.f;
  for (int i = tid; i < CS; i += 256) sx += expf(hlog[i] - M);
  for (int off = 32; off; off >>= 1) sx += __shfl_xor(sx, off, 64);
  __syncthreads();
  if (lane == 0) redm[w] = sx;
  __syncthreads();
  if (tid == 0) hl_s = M + logf(redm[0] + redm[1] + redm[2] + redm[3]);
  __syncthreads();
  const float hlse = hl_s;

  // 16 nodes -> 4 -> 1
  const u16* src = nodes + (size_t)n * 16 * 4096;
  const float* sc = nsc + n * 16;
  u16* scr = scratch + (size_t)n * 64 * 4096;
  float* scs = ssc + n * 64;
  for (int i = 0; i < 4; ++i) {
    comb4_body(lds, wpm,
        src + (size_t)(4 * i) * 4096, src + (size_t)(4 * i + 1) * 4096,
        src + (size_t)(4 * i + 2) * 4096, src + (size_t)(4 * i + 3) * 4096,
        sc[4 * i], sc[4 * i + 1], sc[4 * i + 2], sc[4 * i + 3],
        scr + (size_t)i * 4096, &scs[i], i & 1, tid);
    __syncthreads();
  }
  comb4_body(lds, wpm, scr, scr + 4096, scr + 2 * 4096, scr + 3 * 4096,
             scs[0], scs[1], scs[2], scs[3], scr + 4 * 4096, &scs[4], 0, tid);
  __syncthreads();

  // final: out[n] = m0 + rootscale + log(sum_i a0lin[i] * rowsum_i(root))
  if (tid < 64) {
    const int i = tid;
    const int w0 = text[n * TT];
    const int cc = w2c[w0];
    const float ev = lall[(size_t)w0 * 64 + i] - logf(esum[cc * 64 + i]);
    float a0 = hlog[cc * 64 + i] - hlse + ev;
    float m0 = a0;
    for (int off = 32; off; off >>= 1) m0 = fmaxf(m0, __shfl_xor(m0, off, 64));
    const float lin = expf(a0 - m0);
    const u16* row = scr + 4 * 4096 + i * 64;
    float rs = 0.f;
#pragma unroll
    for (int e8 = 0; e8 < 8; ++e8) {
      const u16x8 v = *reinterpret_cast<const u16x8*>(row + e8 * 8);
#pragma unroll
      for (int e = 0; e < 8; ++e) rs += bf2f(v[e]);
    }
    float v = lin * rs;
    for (int off = 32; off; off >>= 1) v += __shfl_xor(v, off, 64);
    if (i == 0) out[n] = m0 + scs[4] + logf(v);
  }
}

// ---------------- emission GEMM (gl2lds gathered staging) ----------------

__global__ __launch_bounds__(256) void emis_k(
    const u16* __restrict__ Wpb, const u16* __restrict__ PHb,
    const float* __restrict__ bp,
    const int* __restrict__ offs, const int* __restrict__ wlist,
    const int* __restrict__ map,
    float* __restrict__ esum, float* __restrict__ logits_all) {
  const int ent = map[blockIdx.x];
  if (ent < 0) return;
  const int c = ent >> 8, blk = ent & 255;
  __shared__ char lds[16384];
  __shared__ int wid_s[64];
  const int tid = threadIdx.x, lane = tid & 63, wid = tid >> 6;
  const int st = offs[c], cnt = offs[c + 1] - st;
  if (tid < 64) {
    const int idx = blk * 64 + tid;
    wid_s[tid] = (idx < cnt) ? wlist[st + idx] : -1;
  }
  __syncthreads();

  f32x4 acc[4];
#pragma unroll
  for (int i = 0; i < 4; ++i) acc[i] = (f32x4){0.f, 0.f, 0.f, 0.f};

  const int ra = wid * 16 + (lane & 15);
  const int rb0 = lane & 15;
  const int ko = (lane >> 4) * 8;
  const u16* Bg = PHb + (size_t)(c * 64) * HD;

  for (int kc = 0; kc < HD; kc += 64) {
    if (kc) __syncthreads();
#pragma unroll
    for (int i = 0; i < 2; ++i) {
      const int cc = i * 256 + tid;
      const int r = cc >> 3, cb = cc & 7;
      const int gq = cb ^ (r & 7);
      const int wv = max(wid_s[r], 0);
      gl2lds16(Wpb + (size_t)wv * HD + kc + gq * 8, (u16*)&lds[cc * 16]);
      gl2lds16(Bg + (size_t)r * HD + kc + gq * 8, (u16*)&lds[8192 + cc * 16]);
    }
    __syncthreads();
#pragma unroll
    for (int kk = 0; kk < 64; kk += 32) {
      const int kb = (kk + ko) * 2;
      const bh8 af = *reinterpret_cast<const bh8*>(&lds[ra * 128 + (kb ^ ((ra & 7) << 4))]);
#pragma unroll
      for (int nj = 0; nj < 4; ++nj) {
        const int rb = nj * 16 + rb0;
        const bh8 bf = *reinterpret_cast<const bh8*>(&lds[8192 + rb * 128 + (kb ^ ((rb & 7) << 4))]);
        acc[nj] = __builtin_amdgcn_mfma_f32_16x16x32_bf16(af, bf, acc[nj], 0, 0, 0);
      }
    }
  }

  const int g = lane >> 4, c0 = lane & 15;
#pragma unroll
  for (int nj = 0; nj < 4; ++nj) {
    float se = 0.f;
#pragma unroll
    for (int reg = 0; reg < 4; ++reg) {
      const int row = wid * 16 + g * 4 + reg;
      const int w = wid_s[row];
      if (w >= 0) {
        const float lg = acc[nj][reg] + bp[w];
        logits_all[(size_t)w * 64 + nj * 16 + c0] = lg;
        se += expf(lg);
      }
    }
    se += __shfl_xor(se, 16, 64);
    se += __shfl_xor(se, 32, 64);
    if (g == 0) atomicAdd(&esum[c * 64 + nj * 16 + c0], se);
  }
}

// ---------------- start head ----------------

__global__ __launch_bounds__(256) void head_dot_k(const float* __restrict__ sh,
                                                  const float* __restrict__ wv,
                                                  const float* __restrict__ bv,
                                                  float* __restrict__ logits) {
  const int tid = threadIdx.x, lane = tid & 63, wid = tid >> 6;
  const int row = blockIdx.x * 4 + wid;
  float s = 0.f;
#pragma unroll
  for (int q = 0; q < 4; ++q)
    s += sh[(size_t)row * HD + q * 64 + lane] * wv[q * 64 + lane];
  for (int off = 32; off; off >>= 1) s += __shfl_xor(s, off, 64);
  if (lane == 0) logits[row] = s + bv[0];
}

// ---------------- host orchestration ----------------

extern "C" void kernel_launch(void* const* d_in, const int* in_sizes, int n_in,
                              void* d_out, int out_size, void* d_ws, size_t ws_size,
                              hipStream_t stream) {
  (void)in_sizes; (void)n_in; (void)out_size; (void)ws_size;
  const int* text = (const int*)d_in[0];
  const int* w2c  = (const int*)d_in[1];
  const float* sec = (const float*)d_in[2];
  const float* ses = (const float*)d_in[3];
  const float* stc = (const float*)d_in[4];
  const float* sts = (const float*)d_in[5];
  const float* nec = (const float*)d_in[6];
  const float* nes = (const float*)d_in[7];
  const float* pec = (const float*)d_in[8];
  const float* pes = (const float*)d_in[9];
  const float* srw1 = (const float*)d_in[10];
  const float* srb1 = (const float*)d_in[11];
  const float* srw2 = (const float*)d_in[12];
  const float* srb2 = (const float*)d_in[13];
  const float* trw1 = (const float*)d_in[14];
  const float* trb1 = (const float*)d_in[15];
  const float* trw2 = (const float*)d_in[16];
  const float* trb2 = (const float*)d_in[17];
  const float* tew1 = (const float*)d_in[18];
  const float* teb1 = (const float*)d_in[19];
  const float* tew2 = (const float*)d_in[20];
  const float* teb2 = (const float*)d_in[21];
  const float* sow = (const float*)d_in[22];
  const float* sob = (const float*)d_in[23];
  const float* tpw = (const float*)d_in[24];
  const float* tpb = (const float*)d_in[25];
  float* out = (float*)d_out;

  char* p = (char*)d_ws;
  auto carve = [&](size_t bytes) -> char* {
    char* r = p; p += (bytes + 255) & ~(size_t)255; return r;
  };
  u16* Wall = (u16*)carve((size_t)WT2 * 2);
  u16* Wpb  = Wall + WTOT;
  u16* EbS  = (u16*)carve((size_t)CS * HD * 2);
  u16* EbT  = (u16*)carve((size_t)CS * HD * 2);
  u16* NSEb = (u16*)carve((size_t)CS * HD * 2);
  u16* EbP  = (u16*)carve((size_t)CS * HD * 2);
  u16* Hb0  = (u16*)carve((size_t)CS * HD * 2);
  u16* Hb1  = (u16*)carve((size_t)CS * HD * 2);
  u16* Hb2  = (u16*)carve((size_t)CS * HD * 2);
  float* SHf = (float*)carve((size_t)CS * HD * 4);
  u16* Xbf  = (u16*)carve((size_t)CS * HD * 2);
  u16* PHb  = (u16*)carve((size_t)CS * HD * 2);
  float* hlog  = (float*)carve(CS * 4);
  float* part  = (float*)carve((size_t)32 * CS * 4);
  float* rlse  = (float*)carve(CS * 4);
  int* offs    = (int*)carve((KCL + 1) * 4);
  int* wlist   = (int*)carve(VV * 4);
  int* bmap    = (int*)carve(MAXB * 4);
  float* esum  = (float*)carve(CS * 4);
  float* lall  = (float*)carve((size_t)VV * 64 * 4);
  u16*   bufA  = (u16*)carve((size_t)NB * 256 * 4096 * 2);
  u16*   bufB  = (u16*)carve((size_t)NB * 64 * 4096 * 2);
  float* scA   = (float*)carve((size_t)NB * 256 * 4);
  float* scB   = (float*)carve((size_t)NB * 256 * 4);

  prep_k<<<NCVT + NEMB + 2, 256, 0, stream>>>(
      srw1, srw2, trw1, trw2, tew1, tew2, tpw, Wall,
      sec, ses, EbS, stc, sts, EbT, nec, nes, NSEb, pec, pes, EbP,
      w2c, offs, wlist, bmap, esum);

  // batched residual MLPs (z = start/trans/term)
  mlp_k<1><<<dim3(4, 128, 3), 256, 0, stream>>>(
      EbS, EbT, EbP, Hb0, Hb1, Hb2, Wall, srb1, trb1, teb1, nullptr, nullptr, nullptr);
  mlp_k<2><<<dim3(4, 128, 3), 256, 0, stream>>>(
      EbS, EbT, EbP, Hb0, Hb1, Hb2, Wall, srb2, trb2, teb2, SHf, Xbf, PHb);

  // transition row-logsumexp (long pole) + head
  rlse_k<<<1024, 512, 0, stream>>>(Xbf, NSEb, part);
  rred_k<<<CS / 256, 256, 0, stream>>>(part, rlse);
  head_dot_k<<<CS / 4, 256, 0, stream>>>(SHf, sow, sob, hlog);

  // emission
  emis_k<<<MAXB, 256, 0, stream>>>(Wpb, PHb, tpb, offs, wlist, bmap, esum, lall);

  // leaves (emit inline; identity leaves in same grid)
  leaf_k<<<dim3(NB * (TT - 1) + NB), 256, 0, stream>>>(
      Xbf, NSEb, rlse, lall, esum, text, w2c, bufA, scA);

  // quad-tree: 256 -> 64 -> 16, then tail (16 -> 4 -> 1 + final)
  comb4_k<<<NB * 64, 256, 0, stream>>>(bufA, scA, bufB, scB, 64);
  comb4_k<<<NB * 16, 256, 0, stream>>>(bufB, scB, bufA, scA, 16);
  tail_k<<<NB, 256, 0, stream>>>(bufA, scA, bufB, scB, hlog, lall, esum, text, w2c, out);
}